// Round 1
// baseline (347.629 us; speedup 1.0000x reference)
//
#include <hip/hip_runtime.h>
#include <hip/hip_bf16.h>
#include <math.h>

#define EPSF 1e-8f

// Icosphere div-1 connectivity, deterministically produced by _icosphere_div1()
// (midpoint-cache order simulated by hand; verified 12*5 + 30*6 = 240 corners).
static constexpr int FI[80][3] = {
  {0,12,14},{11,13,12},{5,14,13},{12,13,14},
  {0,14,16},{5,15,14},{1,16,15},{14,15,16},
  {0,16,18},{1,17,16},{7,18,17},{16,17,18},
  {0,18,20},{7,19,18},{10,20,19},{18,19,20},
  {0,20,12},{10,21,20},{11,12,21},{20,21,12},
  {1,15,23},{5,22,15},{9,23,22},{15,22,23},
  {5,13,25},{11,24,13},{4,25,24},{13,24,25},
  {11,21,27},{10,26,21},{2,27,26},{21,26,27},
  {10,19,29},{7,28,19},{6,29,28},{19,28,29},
  {7,17,31},{1,30,17},{8,31,30},{17,30,31},
  {3,32,34},{9,33,32},{4,34,33},{32,33,34},
  {3,34,36},{4,35,34},{2,36,35},{34,35,36},
  {3,36,38},{2,37,36},{6,38,37},{36,37,38},
  {3,38,40},{6,39,38},{8,40,39},{38,39,40},
  {3,40,32},{8,41,40},{9,32,41},{40,41,32},
  {4,33,25},{9,22,33},{5,25,22},{33,22,25},
  {2,35,27},{4,24,35},{11,27,24},{35,24,27},
  {6,37,29},{2,26,37},{10,29,26},{37,26,29},
  {8,39,31},{6,28,39},{7,31,28},{39,28,31},
  {9,41,23},{8,30,41},{1,23,30},{41,30,23}
};

// ---------------------------------------------------------------------------
// Phase 1: cage shrink optimization + keypoint offset. One block per (b, v).
// c stays on the ray s * c0; dist^2(s) = a*s^2 - 2b*s + c per shape point.
// ---------------------------------------------------------------------------
__global__ __launch_bounds__(256) void k_cage(
    const float* __restrict__ catModel,   // (B,6144,3)
    const float* __restrict__ tv,         // (1,3,42)
    const float* __restrict__ catKeys,    // (B,8,3)
    const float* __restrict__ insKeys,    // (B,8,3)
    const float* __restrict__ catInflu,   // (B,8,42)
    float* __restrict__ cage,             // (B,42,3) out
    float* __restrict__ ncage)            // (B,42,3) out
{
  const int b = blockIdx.x / 42, v = blockIdx.x % 42;
  const int tid = threadIdx.x;
  const float c0x = tv[v], c0y = tv[42 + v], c0z = tv[84 + v];
  const float a = c0x*c0x + c0y*c0y + c0z*c0z;

  float pb2[24], pc[24];
  const float* P = catModel + (size_t)b * 6144 * 3;
  #pragma unroll
  for (int j = 0; j < 24; ++j) {
    int n = tid + j * 256;
    float px = P[n*3+0], py = P[n*3+1], pz = P[n*3+2];
    pb2[j] = -2.0f * (c0x*px + c0y*py + c0z*pz);
    pc[j]  = px*px + py*py + pz*pz;
  }

  __shared__ float red[4];
  float s = 1.0f;
  for (int t = 0; t < 100; ++t) {
    float m = 1e30f;
    #pragma unroll
    for (int j = 0; j < 24; ++j)
      m = fminf(m, fmaf(fmaf(a, s, pb2[j]), s, pc[j]));
    #pragma unroll
    for (int off = 32; off; off >>= 1)
      m = fminf(m, __shfl_xor(m, off, 64));
    if ((tid & 63) == 0) red[tid >> 6] = m;
    __syncthreads();
    m = fminf(fminf(red[0], red[1]), fminf(red[2], red[3]));
    __syncthreads();
    if (m > 0.16f) s *= 0.99f;   // min dist > 0.4  <=>  min dist^2 > 0.16
  }

  if (tid < 3) {
    const int d = tid;
    const float cg = s * tv[d*42 + v];
    float off = 0.0f;
    #pragma unroll
    for (int k = 0; k < 8; ++k)
      off += (insKeys[(b*8+k)*3 + d] - catKeys[(b*8+k)*3 + d]) * catInflu[(b*8+k)*42 + v];
    cage [(b*42 + v)*3 + d] = cg;
    ncage[(b*42 + v)*3 + d] = cg + off;
  }
}

// ---------------------------------------------------------------------------
// Phase 2: MVC weights + deformation. One thread per (b, p).
// Faces fully unrolled with constexpr indices -> W[42] lives in registers.
// sin(theta), sin(h), sin(h - theta) via exact identities from asin inputs.
// ---------------------------------------------------------------------------
__global__ __launch_bounds__(256) void k_mvc(
    const float* __restrict__ catModel, // (B,6144,3)
    const float* __restrict__ cage,     // (B,42,3)
    const float* __restrict__ ncage,    // (B,42,3)
    float* __restrict__ outDef)         // (B,6144,3)
{
  const int b = blockIdx.x / 24;
  const int p = (blockIdx.x % 24) * 256 + threadIdx.x;

  __shared__ float cv[126], nv[126];
  if (threadIdx.x < 126) {
    cv[threadIdx.x] = cage [b*126 + threadIdx.x];
    nv[threadIdx.x] = ncage[b*126 + threadIdx.x];
  }
  __syncthreads();

  const float qx = catModel[((size_t)b*6144 + p)*3 + 0];
  const float qy = catModel[((size_t)b*6144 + p)*3 + 1];
  const float qz = catModel[((size_t)b*6144 + p)*3 + 2];

  float W[42];
  #pragma unroll
  for (int i = 0; i < 42; ++i) W[i] = 0.0f;

  #pragma unroll
  for (int f = 0; f < 80; ++f) {
    const int i0 = FI[f][0], i1 = FI[f][1], i2 = FI[f][2];

    float e0x = cv[i0*3+0]-qx, e0y = cv[i0*3+1]-qy, e0z = cv[i0*3+2]-qz;
    float e1x = cv[i1*3+0]-qx, e1y = cv[i1*3+1]-qy, e1z = cv[i1*3+2]-qz;
    float e2x = cv[i2*3+0]-qx, e2y = cv[i2*3+1]-qy, e2z = cv[i2*3+2]-qz;
    float d0 = sqrtf(e0x*e0x + e0y*e0y + e0z*e0z);
    float d1 = sqrtf(e1x*e1x + e1y*e1y + e1z*e1z);
    float d2 = sqrtf(e2x*e2x + e2y*e2y + e2z*e2z);
    float r0 = 1.0f / fmaxf(d0, EPSF);
    float r1 = 1.0f / fmaxf(d1, EPSF);
    float r2 = 1.0f / fmaxf(d2, EPSF);
    float u0x = e0x*r0, u0y = e0y*r0, u0z = e0z*r0;
    float u1x = e1x*r1, u1y = e1y*r1, u1z = e1z*r1;
    float u2x = e2x*r2, u2y = e2y*r2, u2z = e2z*r2;

    // l_k = |u_{k+1} - u_{k-1}|
    float ax_ = u1x-u2x, ay_ = u1y-u2y, az_ = u1z-u2z;
    float bx_ = u2x-u0x, by_ = u2y-u0y, bz_ = u2z-u0z;
    float cx_ = u0x-u1x, cy_ = u0y-u1y, cz_ = u0z-u1z;
    float l0 = sqrtf(ax_*ax_ + ay_*ay_ + az_*az_);
    float l1 = sqrtf(bx_*bx_ + by_*by_ + bz_*bz_);
    float l2 = sqrtf(cx_*cx_ + cy_*cy_ + cz_*cz_);

    float s0 = fminf(0.5f*l0, 1.0f);
    float s1 = fminf(0.5f*l1, 1.0f);
    float s2 = fminf(0.5f*l2, 1.0f);
    float th0 = 2.0f*asinf(s0), th1 = 2.0f*asinf(s1), th2 = 2.0f*asinf(s2);
    float co0 = sqrtf(fmaxf(fmaf(-s0, s0, 1.0f), 0.0f));
    float co1 = sqrtf(fmaxf(fmaf(-s1, s1, 1.0f), 0.0f));
    float co2 = sqrtf(fmaxf(fmaf(-s2, s2, 1.0f), 0.0f));
    float st0 = 2.0f*s0*co0;   // sin(theta_k), exact identity
    float st1 = 2.0f*s1*co1;
    float st2 = 2.0f*s2*co2;

    // sin/cos of h = a0+a1+a2 (a_k = asin(s_k)) by angle-sum expansion
    float Sh = s0*co1*co2 + co0*s1*co2 + co0*co1*s2 - s0*s1*s2;
    float Ch = co0*co1*co2 - s0*s1*co2 - s0*co1*s2 - co0*s1*s2;
    // sin(h - theta_k) = Sh*cos(2ak) - Ch*sin(2ak)
    float sh0 = Sh*fmaf(-2.0f*s0, s0, 1.0f) - Ch*st0;
    float sh1 = Sh*fmaf(-2.0f*s1, s1, 1.0f) - Ch*st1;
    float sh2 = Sh*fmaf(-2.0f*s2, s2, 1.0f) - Ch*st2;

    float c0 = 2.0f*Sh*sh0 / fmaxf(st1*st2, EPSF) - 1.0f;
    float c1 = 2.0f*Sh*sh1 / fmaxf(st2*st0, EPSF) - 1.0f;
    float c2 = 2.0f*Sh*sh2 / fmaxf(st0*st1, EPSF) - 1.0f;

    float det = u0x*(u1y*u2z - u1z*u2y)
              + u0y*(u1z*u2x - u1x*u2z)
              + u0z*(u1x*u2y - u1y*u2x);
    float sg = (det > 0.0f) ? 1.0f : ((det < 0.0f) ? -1.0f : 0.0f);
    float q0 = sg * sqrtf(fmaxf(fmaf(-c0, c0, 1.0f), 0.0f));
    float q1 = sg * sqrtf(fmaxf(fmaf(-c1, c1, 1.0f), 0.0f));
    float q2 = sg * sqrtf(fmaxf(fmaf(-c2, c2, 1.0f), 0.0f));
    bool valid = (fabsf(q0) > EPSF) && (fabsf(q1) > EPSF) && (fabsf(q2) > EPSF);

    float n0 = th0 - c1*th2 - c2*th1;
    float n1 = th1 - c2*th0 - c0*th2;
    float n2 = th2 - c0*th1 - c1*th0;
    float de0 = d0*st1*q2;
    float de1 = d1*st2*q0;
    float de2 = d2*st0*q1;
    de0 = (fabsf(de0) > EPSF) ? de0 : ((de0 >= 0.0f) ? EPSF : -EPSF);
    de1 = (fabsf(de1) > EPSF) ? de1 : ((de1 >= 0.0f) ? EPSF : -EPSF);
    de2 = (fabsf(de2) > EPSF) ? de2 : ((de2 >= 0.0f) ? EPSF : -EPSF);

    if (valid) {
      W[i0] += n0/de0;
      W[i1] += n1/de1;
      W[i2] += n2/de2;
    }
  }

  float sW = 0.0f;
  #pragma unroll
  for (int i = 0; i < 42; ++i) sW += W[i];
  sW = (fabsf(sW) > EPSF) ? sW : EPSF;
  float inv = 1.0f / sW;

  float dx = 0.0f, dy = 0.0f, dz = 0.0f;
  #pragma unroll
  for (int i = 0; i < 42; ++i) {
    float w = W[i] * inv;
    dx = fmaf(w, nv[i*3+0], dx);
    dy = fmaf(w, nv[i*3+1], dy);
    dz = fmaf(w, nv[i*3+2], dz);
  }
  outDef[((size_t)b*6144 + p)*3 + 0] = dx;
  outDef[((size_t)b*6144 + p)*3 + 1] = dy;
  outDef[((size_t)b*6144 + p)*3 + 2] = dz;
}

// ---------------------------------------------------------------------------
// Phase 3: chamfer min distances. Symmetric kernel, run twice.
// d2 = |r|^2 + (|c|^2 - 2 r.c); track min of the parenthesis, add |r|^2 after.
// grid = B(4) * row-tiles(12, 512 rows each, 2/thread) * col-chunks(8, 768)
// ---------------------------------------------------------------------------
__global__ __launch_bounds__(256) void k_chamfer(
    const float* __restrict__ rows,   // (B,6144,3)
    const float* __restrict__ cols,   // (B,6144,3)
    unsigned*    __restrict__ minout) // (B*6144) float-as-uint, pre-init +inf
{
  const int bx  = blockIdx.x;
  const int b   = bx / 96;
  const int rt  = (bx % 96) / 8;
  const int cc  = bx % 8;
  const int tid = threadIdx.x;

  const float* R = rows + (size_t)b * 6144 * 3;
  const float* C = cols + (size_t)b * 6144 * 3;

  const int r0 = rt*512 + tid;
  const int r1 = r0 + 256;
  const float r0x = R[r0*3+0], r0y = R[r0*3+1], r0z = R[r0*3+2];
  const float r1x = R[r1*3+0], r1y = R[r1*3+1], r1z = R[r1*3+2];

  __shared__ float4 tile[256];
  float m0 = 1e30f, m1 = 1e30f;

  for (int t = 0; t < 3; ++t) {
    int c = cc*768 + t*256 + tid;
    float cx = C[c*3+0], cy = C[c*3+1], cz = C[c*3+2];
    tile[tid] = make_float4(cx, cy, cz, cx*cx + cy*cy + cz*cz);
    __syncthreads();
    #pragma unroll 8
    for (int j = 0; j < 256; ++j) {
      float4 q = tile[j];
      float dot0 = q.x*r0x + q.y*r0y + q.z*r0z;
      m0 = fminf(m0, fmaf(-2.0f, dot0, q.w));
      float dot1 = q.x*r1x + q.y*r1y + q.z*r1z;
      m1 = fminf(m1, fmaf(-2.0f, dot1, q.w));
    }
    __syncthreads();
  }

  const float rn0 = r0x*r0x + r0y*r0y + r0z*r0z;
  const float rn1 = r1x*r1x + r1y*r1y + r1z*r1z;
  atomicMin(&minout[b*6144 + r0], __float_as_uint(m0 + rn0));
  atomicMin(&minout[b*6144 + r1], __float_as_uint(m1 + rn1));
}

__global__ __launch_bounds__(256) void k_init(unsigned* __restrict__ p, int n) {
  int i = blockIdx.x * 256 + threadIdx.x;
  if (i < n) p[i] = 0x7F800000u;  // +inf
}

__global__ __launch_bounds__(256) void k_loss(
    const unsigned* __restrict__ mins,  // 2*24576 entries (rowmin, colmin)
    float* __restrict__ out)
{
  float s = 0.0f;
  for (int i = threadIdx.x; i < 49152; i += 256)
    s += __uint_as_float(mins[i]);
  #pragma unroll
  for (int off = 32; off; off >>= 1) s += __shfl_xor(s, off, 64);
  __shared__ float red[4];
  if ((threadIdx.x & 63) == 0) red[threadIdx.x >> 6] = s;
  __syncthreads();
  if (threadIdx.x == 0)
    out[0] = (red[0] + red[1] + red[2] + red[3]) * (1.0f / 24576.0f);
}

// ---------------------------------------------------------------------------
extern "C" void kernel_launch(void* const* d_in, const int* in_sizes, int n_in,
                              void* d_out, int out_size, void* d_ws, size_t ws_size,
                              hipStream_t stream) {
  const float* catModel = (const float*)d_in[0];  // (4,6144,3)
  const float* catKeys  = (const float*)d_in[1];  // (4,8,3)
  const float* catInflu = (const float*)d_in[2];  // (4,8,42)
  const float* insKeys  = (const float*)d_in[3];  // (4,8,3)
  const float* insModel = (const float*)d_in[4];  // (4,6144,3)
  const float* tv       = (const float*)d_in[5];  // (1,3,42)
  // d_in[6] = template_faces, baked in as FI[][]

  float* out = (float*)d_out;       // [catModel | insModel | deformed | loss]
  float* ws  = (float*)d_ws;
  float*    cage  = ws;                       // 504 floats (pad to 512)
  float*    ncage = ws + 512;                 // 504 floats
  unsigned* mins  = (unsigned*)(ws + 1024);   // 49152 uints

  // outputs 0 and 1 are verbatim input copies
  hipMemcpyAsync(out,         d_in[0], 73728*sizeof(float), hipMemcpyDeviceToDevice, stream);
  hipMemcpyAsync(out + 73728, d_in[4], 73728*sizeof(float), hipMemcpyDeviceToDevice, stream);

  k_init<<<192, 256, 0, stream>>>(mins, 49152);
  k_cage<<<168, 256, 0, stream>>>(catModel, tv, catKeys, insKeys, catInflu, cage, ncage);
  k_mvc <<< 96, 256, 0, stream>>>(catModel, cage, ncage, out + 147456);
  k_chamfer<<<384, 256, 0, stream>>>(out + 147456, insModel, mins);          // min over ins (rowmin)
  k_chamfer<<<384, 256, 0, stream>>>(insModel, out + 147456, mins + 24576);  // min over def (colmin)
  k_loss<<<1, 256, 0, stream>>>(mins, out + 221184);
}

// Round 2
// 249.396 us; speedup vs baseline: 1.3939x; 1.3939x over previous
//
#include <hip/hip_runtime.h>
#include <hip/hip_bf16.h>
#include <math.h>

#define EPSF 1e-8f

// Icosphere div-1 connectivity, deterministically produced by _icosphere_div1().
static constexpr int FI[80][3] = {
  {0,12,14},{11,13,12},{5,14,13},{12,13,14},
  {0,14,16},{5,15,14},{1,16,15},{14,15,16},
  {0,16,18},{1,17,16},{7,18,17},{16,17,18},
  {0,18,20},{7,19,18},{10,20,19},{18,19,20},
  {0,20,12},{10,21,20},{11,12,21},{20,21,12},
  {1,15,23},{5,22,15},{9,23,22},{15,22,23},
  {5,13,25},{11,24,13},{4,25,24},{13,24,25},
  {11,21,27},{10,26,21},{2,27,26},{21,26,27},
  {10,19,29},{7,28,19},{6,29,28},{19,28,29},
  {7,17,31},{1,30,17},{8,31,30},{17,30,31},
  {3,32,34},{9,33,32},{4,34,33},{32,33,34},
  {3,34,36},{4,35,34},{2,36,35},{34,35,36},
  {3,36,38},{2,37,36},{6,38,37},{36,37,38},
  {3,38,40},{6,39,38},{8,40,39},{38,39,40},
  {3,40,32},{8,41,40},{9,32,41},{40,41,32},
  {4,33,25},{9,22,33},{5,25,22},{33,22,25},
  {2,35,27},{4,24,35},{11,27,24},{35,24,27},
  {6,37,29},{2,26,37},{10,29,26},{37,26,29},
  {8,39,31},{6,28,39},{7,31,28},{39,28,31},
  {9,41,23},{8,30,41},{1,23,30},{41,30,23}
};

// ---------------------------------------------------------------------------
// Phase 1: cage shrink. s_final = 0.99^k, k = first t in [0,100) with
// min-dist^2(0.99^t) <= 0.16 (once the condition fails it never resumes).
// All 100 candidate scales evaluated straight-line; one barrier per block.
// ---------------------------------------------------------------------------
__global__ __launch_bounds__(256) void k_cage(
    const float* __restrict__ catModel,   // (B,6144,3)
    const float* __restrict__ tv,         // (1,3,42)
    const float* __restrict__ catKeys,    // (B,8,3)
    const float* __restrict__ insKeys,    // (B,8,3)
    const float* __restrict__ catInflu,   // (B,8,42)
    float* __restrict__ cage,             // (B,42,3) out
    float* __restrict__ ncage)            // (B,42,3) out
{
  const int b = blockIdx.x / 42, v = blockIdx.x % 42;
  const int tid = threadIdx.x;
  const int lane = tid & 63, w = tid >> 6;
  const float c0x = tv[v], c0y = tv[42 + v], c0z = tv[84 + v];
  const float a = c0x*c0x + c0y*c0y + c0z*c0z;

  float pb2[24], pc[24];
  const float* P = catModel + (size_t)b * 6144 * 3;
  #pragma unroll
  for (int j = 0; j < 24; ++j) {
    int n = tid + j * 256;
    float px = P[n*3+0], py = P[n*3+1], pz = P[n*3+2];
    pb2[j] = -2.0f * (c0x*px + c0y*py + c0z*pz);
    pc[j]  = px*px + py*py + pz*pz;
  }

  __shared__ float mm[4][100];
  __shared__ float sfin;

  float s = 1.0f;
  for (int t = 0; t < 100; ++t) {
    float m = 1e30f;
    #pragma unroll
    for (int j = 0; j < 24; ++j)
      m = fminf(m, fmaf(fmaf(a, s, pb2[j]), s, pc[j]));
    #pragma unroll
    for (int off = 32; off; off >>= 1)
      m = fminf(m, __shfl_xor(m, off, 64));
    if (lane == 0) mm[w][t] = m;
    s *= 0.99f;
  }
  __syncthreads();

  if (tid == 0) {
    int k = 100;
    for (int t = 0; t < 100; ++t) {
      float mt = fminf(fminf(mm[0][t], mm[1][t]), fminf(mm[2][t], mm[3][t]));
      if (mt <= 0.16f) { k = t; break; }
    }
    float sf = 1.0f;                 // replicate reference's float rounding
    for (int i = 0; i < k; ++i) sf *= 0.99f;
    sfin = sf;
  }
  __syncthreads();

  if (tid < 3) {
    const int d = tid;
    const float cg = sfin * tv[d*42 + v];
    float off = 0.0f;
    #pragma unroll
    for (int k = 0; k < 8; ++k)
      off += (insKeys[(b*8+k)*3 + d] - catKeys[(b*8+k)*3 + d]) * catInflu[(b*8+k)*42 + v];
    cage [(b*42 + v)*3 + d] = cg;
    ncage[(b*42 + v)*3 + d] = cg + off;
  }
}

// ---------------------------------------------------------------------------
// Phase 2: MVC + deform, no W[42] array: normalization is by scalar sum, so
// accumulate only (sW, dx, dy, dz). 64 points/block; 4 waves split the 80
// faces (20 each); 4-scalar LDS reduction at the end. No spill possible.
// ---------------------------------------------------------------------------
__global__ __launch_bounds__(256) void k_mvc(
    const float* __restrict__ catModel, // (B,6144,3)
    const float* __restrict__ cage,     // (B,42,3)
    const float* __restrict__ ncage,    // (B,42,3)
    float* __restrict__ outDef)         // (B,6144,3)
{
  const int b    = blockIdx.x / 96;
  const int pblk = blockIdx.x % 96;
  const int lane = threadIdx.x & 63;
  const int w    = threadIdx.x >> 6;
  const int p    = pblk * 64 + lane;

  __shared__ float cv[126], nv[126];
  __shared__ float red[4][4][64];   // [wave][component][lane] — conflict-free
  if (threadIdx.x < 126) {
    cv[threadIdx.x] = cage [b*126 + threadIdx.x];
    nv[threadIdx.x] = ncage[b*126 + threadIdx.x];
  }
  __syncthreads();

  const float qx = catModel[((size_t)b*6144 + p)*3 + 0];
  const float qy = catModel[((size_t)b*6144 + p)*3 + 1];
  const float qz = catModel[((size_t)b*6144 + p)*3 + 2];

  float sW = 0.0f, dx = 0.0f, dy = 0.0f, dz = 0.0f;

  for (int f = w*20; f < w*20 + 20; ++f) {
    const int i0 = FI[f][0], i1 = FI[f][1], i2 = FI[f][2];

    float e0x = cv[i0*3+0]-qx, e0y = cv[i0*3+1]-qy, e0z = cv[i0*3+2]-qz;
    float e1x = cv[i1*3+0]-qx, e1y = cv[i1*3+1]-qy, e1z = cv[i1*3+2]-qz;
    float e2x = cv[i2*3+0]-qx, e2y = cv[i2*3+1]-qy, e2z = cv[i2*3+2]-qz;
    float d0 = sqrtf(e0x*e0x + e0y*e0y + e0z*e0z);
    float d1 = sqrtf(e1x*e1x + e1y*e1y + e1z*e1z);
    float d2 = sqrtf(e2x*e2x + e2y*e2y + e2z*e2z);
    float r0 = 1.0f / fmaxf(d0, EPSF);
    float r1 = 1.0f / fmaxf(d1, EPSF);
    float r2 = 1.0f / fmaxf(d2, EPSF);
    float u0x = e0x*r0, u0y = e0y*r0, u0z = e0z*r0;
    float u1x = e1x*r1, u1y = e1y*r1, u1z = e1z*r1;
    float u2x = e2x*r2, u2y = e2y*r2, u2z = e2z*r2;

    float ax_ = u1x-u2x, ay_ = u1y-u2y, az_ = u1z-u2z;
    float bx_ = u2x-u0x, by_ = u2y-u0y, bz_ = u2z-u0z;
    float cx_ = u0x-u1x, cy_ = u0y-u1y, cz_ = u0z-u1z;
    float l0 = sqrtf(ax_*ax_ + ay_*ay_ + az_*az_);
    float l1 = sqrtf(bx_*bx_ + by_*by_ + bz_*bz_);
    float l2 = sqrtf(cx_*cx_ + cy_*cy_ + cz_*cz_);

    float s0 = fminf(0.5f*l0, 1.0f);
    float s1 = fminf(0.5f*l1, 1.0f);
    float s2 = fminf(0.5f*l2, 1.0f);
    float th0 = 2.0f*asinf(s0), th1 = 2.0f*asinf(s1), th2 = 2.0f*asinf(s2);
    float co0 = sqrtf(fmaxf(fmaf(-s0, s0, 1.0f), 0.0f));
    float co1 = sqrtf(fmaxf(fmaf(-s1, s1, 1.0f), 0.0f));
    float co2 = sqrtf(fmaxf(fmaf(-s2, s2, 1.0f), 0.0f));
    float st0 = 2.0f*s0*co0;   // sin(theta_k), exact identity
    float st1 = 2.0f*s1*co1;
    float st2 = 2.0f*s2*co2;

    // sin/cos of h = a0+a1+a2 (a_k = asin(s_k)) by angle-sum expansion
    float Sh = s0*co1*co2 + co0*s1*co2 + co0*co1*s2 - s0*s1*s2;
    float Ch = co0*co1*co2 - s0*s1*co2 - s0*co1*s2 - co0*s1*s2;
    // sin(h - theta_k) = Sh*cos(2ak) - Ch*sin(2ak)
    float sh0 = Sh*fmaf(-2.0f*s0, s0, 1.0f) - Ch*st0;
    float sh1 = Sh*fmaf(-2.0f*s1, s1, 1.0f) - Ch*st1;
    float sh2 = Sh*fmaf(-2.0f*s2, s2, 1.0f) - Ch*st2;

    float c0 = 2.0f*Sh*sh0 / fmaxf(st1*st2, EPSF) - 1.0f;
    float c1 = 2.0f*Sh*sh1 / fmaxf(st2*st0, EPSF) - 1.0f;
    float c2 = 2.0f*Sh*sh2 / fmaxf(st0*st1, EPSF) - 1.0f;

    float det = u0x*(u1y*u2z - u1z*u2y)
              + u0y*(u1z*u2x - u1x*u2z)
              + u0z*(u1x*u2y - u1y*u2x);
    float sg = (det > 0.0f) ? 1.0f : ((det < 0.0f) ? -1.0f : 0.0f);
    float q0 = sg * sqrtf(fmaxf(fmaf(-c0, c0, 1.0f), 0.0f));
    float q1 = sg * sqrtf(fmaxf(fmaf(-c1, c1, 1.0f), 0.0f));
    float q2 = sg * sqrtf(fmaxf(fmaf(-c2, c2, 1.0f), 0.0f));
    bool valid = (fabsf(q0) > EPSF) && (fabsf(q1) > EPSF) && (fabsf(q2) > EPSF);

    float n0 = th0 - c1*th2 - c2*th1;
    float n1 = th1 - c2*th0 - c0*th2;
    float n2 = th2 - c0*th1 - c1*th0;
    float de0 = d0*st1*q2;
    float de1 = d1*st2*q0;
    float de2 = d2*st0*q1;
    de0 = (fabsf(de0) > EPSF) ? de0 : ((de0 >= 0.0f) ? EPSF : -EPSF);
    de1 = (fabsf(de1) > EPSF) ? de1 : ((de1 >= 0.0f) ? EPSF : -EPSF);
    de2 = (fabsf(de2) > EPSF) ? de2 : ((de2 >= 0.0f) ? EPSF : -EPSF);

    if (valid) {
      float w0 = n0/de0, w1 = n1/de1, w2 = n2/de2;
      sW += w0 + w1 + w2;
      dx = fmaf(w0, nv[i0*3+0], fmaf(w1, nv[i1*3+0], fmaf(w2, nv[i2*3+0], dx)));
      dy = fmaf(w0, nv[i0*3+1], fmaf(w1, nv[i1*3+1], fmaf(w2, nv[i2*3+1], dy)));
      dz = fmaf(w0, nv[i0*3+2], fmaf(w1, nv[i1*3+2], fmaf(w2, nv[i2*3+2], dz)));
    }
  }

  red[w][0][lane] = sW;
  red[w][1][lane] = dx;
  red[w][2][lane] = dy;
  red[w][3][lane] = dz;
  __syncthreads();

  if (w == 0) {
    float S = red[0][0][lane] + red[1][0][lane] + red[2][0][lane] + red[3][0][lane];
    float X = red[0][1][lane] + red[1][1][lane] + red[2][1][lane] + red[3][1][lane];
    float Y = red[0][2][lane] + red[1][2][lane] + red[2][2][lane] + red[3][2][lane];
    float Z = red[0][3][lane] + red[1][3][lane] + red[2][3][lane] + red[3][3][lane];
    S = (fabsf(S) > EPSF) ? S : EPSF;
    float inv = 1.0f / S;
    outDef[((size_t)b*6144 + p)*3 + 0] = X * inv;
    outDef[((size_t)b*6144 + p)*3 + 1] = Y * inv;
    outDef[((size_t)b*6144 + p)*3 + 2] = Z * inv;
  }
}

// ---------------------------------------------------------------------------
// Phase 3: chamfer mins. 4 rows/thread (LDS read amortized over 20 VALU).
// grid = B(4) x row-tiles(6 x 1024) x col-chunks(24 x 256) = 576 blocks
// ---------------------------------------------------------------------------
__global__ __launch_bounds__(256) void k_chamfer(
    const float* __restrict__ rows,   // (B,6144,3)
    const float* __restrict__ cols,   // (B,6144,3)
    unsigned*    __restrict__ minout) // (B*6144) float-as-uint, pre-init +inf
{
  const int b   = blockIdx.x / 144;
  const int rt  = (blockIdx.x % 144) / 24;
  const int cc  = blockIdx.x % 24;
  const int tid = threadIdx.x;

  const float* R = rows + (size_t)b * 6144 * 3;
  const float* C = cols + (size_t)b * 6144 * 3;

  const int r0 = rt*1024 + tid;
  const int r1 = r0 + 256, r2 = r0 + 512, r3 = r0 + 768;
  const float r0x = R[r0*3+0], r0y = R[r0*3+1], r0z = R[r0*3+2];
  const float r1x = R[r1*3+0], r1y = R[r1*3+1], r1z = R[r1*3+2];
  const float r2x = R[r2*3+0], r2y = R[r2*3+1], r2z = R[r2*3+2];
  const float r3x = R[r3*3+0], r3y = R[r3*3+1], r3z = R[r3*3+2];

  __shared__ float4 tile[256];
  {
    int c = cc*256 + tid;
    float cx = C[c*3+0], cy = C[c*3+1], cz = C[c*3+2];
    tile[tid] = make_float4(cx, cy, cz, cx*cx + cy*cy + cz*cz);
  }
  __syncthreads();

  float m0 = 1e30f, m1 = 1e30f, m2 = 1e30f, m3 = 1e30f;
  #pragma unroll 8
  for (int j = 0; j < 256; ++j) {
    float4 q = tile[j];
    m0 = fminf(m0, fmaf(-2.0f, q.x*r0x + q.y*r0y + q.z*r0z, q.w));
    m1 = fminf(m1, fmaf(-2.0f, q.x*r1x + q.y*r1y + q.z*r1z, q.w));
    m2 = fminf(m2, fmaf(-2.0f, q.x*r2x + q.y*r2y + q.z*r2z, q.w));
    m3 = fminf(m3, fmaf(-2.0f, q.x*r3x + q.y*r3y + q.z*r3z, q.w));
  }

  atomicMin(&minout[b*6144 + r0], __float_as_uint(m0 + (r0x*r0x + r0y*r0y + r0z*r0z)));
  atomicMin(&minout[b*6144 + r1], __float_as_uint(m1 + (r1x*r1x + r1y*r1y + r1z*r1z)));
  atomicMin(&minout[b*6144 + r2], __float_as_uint(m2 + (r2x*r2x + r2y*r2y + r2z*r2z)));
  atomicMin(&minout[b*6144 + r3], __float_as_uint(m3 + (r3x*r3x + r3y*r3y + r3z*r3z)));
}

__global__ __launch_bounds__(256) void k_init(unsigned* __restrict__ p, int n) {
  int i = blockIdx.x * 256 + threadIdx.x;
  if (i < n) p[i] = 0x7F800000u;  // +inf
}

__global__ __launch_bounds__(256) void k_loss(
    const unsigned* __restrict__ mins,  // 2*24576 entries (rowmin, colmin)
    float* __restrict__ out)
{
  float s = 0.0f;
  for (int i = threadIdx.x; i < 49152; i += 256)
    s += __uint_as_float(mins[i]);
  #pragma unroll
  for (int off = 32; off; off >>= 1) s += __shfl_xor(s, off, 64);
  __shared__ float red[4];
  if ((threadIdx.x & 63) == 0) red[threadIdx.x >> 6] = s;
  __syncthreads();
  if (threadIdx.x == 0)
    out[0] = (red[0] + red[1] + red[2] + red[3]) * (1.0f / 24576.0f);
}

// ---------------------------------------------------------------------------
extern "C" void kernel_launch(void* const* d_in, const int* in_sizes, int n_in,
                              void* d_out, int out_size, void* d_ws, size_t ws_size,
                              hipStream_t stream) {
  const float* catModel = (const float*)d_in[0];  // (4,6144,3)
  const float* catKeys  = (const float*)d_in[1];  // (4,8,3)
  const float* catInflu = (const float*)d_in[2];  // (4,8,42)
  const float* insKeys  = (const float*)d_in[3];  // (4,8,3)
  const float* insModel = (const float*)d_in[4];  // (4,6144,3)
  const float* tv       = (const float*)d_in[5];  // (1,3,42)
  // d_in[6] = template_faces, baked in as FI[][]

  float* out = (float*)d_out;       // [catModel | insModel | deformed | loss]
  float* ws  = (float*)d_ws;
  float*    cage  = ws;                       // 504 floats (pad to 512)
  float*    ncage = ws + 512;                 // 504 floats
  unsigned* mins  = (unsigned*)(ws + 1024);   // 49152 uints

  // outputs 0 and 1 are verbatim input copies
  hipMemcpyAsync(out,         d_in[0], 73728*sizeof(float), hipMemcpyDeviceToDevice, stream);
  hipMemcpyAsync(out + 73728, d_in[4], 73728*sizeof(float), hipMemcpyDeviceToDevice, stream);

  k_init<<<192, 256, 0, stream>>>(mins, 49152);
  k_cage<<<168, 256, 0, stream>>>(catModel, tv, catKeys, insKeys, catInflu, cage, ncage);
  k_mvc <<<384, 256, 0, stream>>>(catModel, cage, ncage, out + 147456);
  k_chamfer<<<576, 256, 0, stream>>>(out + 147456, insModel, mins);          // min over ins (rowmin)
  k_chamfer<<<576, 256, 0, stream>>>(insModel, out + 147456, mins + 24576);  // min over def (colmin)
  k_loss<<<1, 256, 0, stream>>>(mins, out + 221184);
}

// Round 3
// 173.245 us; speedup vs baseline: 2.0066x; 1.4396x over previous
//
#include <hip/hip_runtime.h>
#include <hip/hip_bf16.h>
#include <math.h>

#define EPSF 1e-8f

// Icosphere div-1 connectivity, deterministically produced by _icosphere_div1().
static constexpr int FI[80][3] = {
  {0,12,14},{11,13,12},{5,14,13},{12,13,14},
  {0,14,16},{5,15,14},{1,16,15},{14,15,16},
  {0,16,18},{1,17,16},{7,18,17},{16,17,18},
  {0,18,20},{7,19,18},{10,20,19},{18,19,20},
  {0,20,12},{10,21,20},{11,12,21},{20,21,12},
  {1,15,23},{5,22,15},{9,23,22},{15,22,23},
  {5,13,25},{11,24,13},{4,25,24},{13,24,25},
  {11,21,27},{10,26,21},{2,27,26},{21,26,27},
  {10,19,29},{7,28,19},{6,29,28},{19,28,29},
  {7,17,31},{1,30,17},{8,31,30},{17,30,31},
  {3,32,34},{9,33,32},{4,34,33},{32,33,34},
  {3,34,36},{4,35,34},{2,36,35},{34,35,36},
  {3,36,38},{2,37,36},{6,38,37},{36,37,38},
  {3,38,40},{6,39,38},{8,40,39},{38,39,40},
  {3,40,32},{8,41,40},{9,32,41},{40,41,32},
  {4,33,25},{9,22,33},{5,25,22},{33,22,25},
  {2,35,27},{4,24,35},{11,27,24},{35,24,27},
  {6,37,29},{2,26,37},{10,29,26},{37,26,29},
  {8,39,31},{6,28,39},{7,31,28},{39,28,31},
  {9,41,23},{8,30,41},{1,23,30},{41,30,23}
};

// ---------------------------------------------------------------------------
// Phase 0: init mins to +inf, loss slot to 0.
// ---------------------------------------------------------------------------
__global__ __launch_bounds__(256) void k_init(unsigned* __restrict__ p, int n,
                                              float* __restrict__ loss) {
  int i = blockIdx.x * 256 + threadIdx.x;
  if (i < n) p[i] = 0x7F800000u;  // +inf
  if (i == 0) loss[0] = 0.0f;
}

// ---------------------------------------------------------------------------
// Phase 1: cage shrink. s_final = 0.99^k, k = first t in [0,100) with
// min-dist^2(0.99^t) <= 0.16. All 100 scales evaluated straight-line.
// ---------------------------------------------------------------------------
__global__ __launch_bounds__(256) void k_cage(
    const float* __restrict__ catModel,   // (B,6144,3)
    const float* __restrict__ tv,         // (1,3,42)
    const float* __restrict__ catKeys,    // (B,8,3)
    const float* __restrict__ insKeys,    // (B,8,3)
    const float* __restrict__ catInflu,   // (B,8,42)
    float* __restrict__ cage,             // (B,42,3) out
    float* __restrict__ ncage)            // (B,42,3) out
{
  const int b = blockIdx.x / 42, v = blockIdx.x % 42;
  const int tid = threadIdx.x;
  const int lane = tid & 63, w = tid >> 6;
  const float c0x = tv[v], c0y = tv[42 + v], c0z = tv[84 + v];
  const float a = c0x*c0x + c0y*c0y + c0z*c0z;

  float pb2[24], pc[24];
  const float* P = catModel + (size_t)b * 6144 * 3;
  #pragma unroll
  for (int j = 0; j < 24; ++j) {
    int n = tid + j * 256;
    float px = P[n*3+0], py = P[n*3+1], pz = P[n*3+2];
    pb2[j] = -2.0f * (c0x*px + c0y*py + c0z*pz);
    pc[j]  = px*px + py*py + pz*pz;
  }

  __shared__ float mm[4][100];
  __shared__ float sfin;

  float s = 1.0f;
  for (int t = 0; t < 100; ++t) {
    float ma = 1e30f, mb = 1e30f, mc = 1e30f, md = 1e30f;
    #pragma unroll
    for (int j = 0; j < 24; j += 4) {        // 4 independent min chains
      ma = fminf(ma, fmaf(fmaf(a, s, pb2[j+0]), s, pc[j+0]));
      mb = fminf(mb, fmaf(fmaf(a, s, pb2[j+1]), s, pc[j+1]));
      mc = fminf(mc, fmaf(fmaf(a, s, pb2[j+2]), s, pc[j+2]));
      md = fminf(md, fmaf(fmaf(a, s, pb2[j+3]), s, pc[j+3]));
    }
    float m = fminf(fminf(ma, mb), fminf(mc, md));
    #pragma unroll
    for (int off = 32; off; off >>= 1)
      m = fminf(m, __shfl_xor(m, off, 64));
    if (lane == 0) mm[w][t] = m;
    s *= 0.99f;
  }
  __syncthreads();

  if (tid == 0) {
    int k = 100;
    for (int t = 0; t < 100; ++t) {
      float mt = fminf(fminf(mm[0][t], mm[1][t]), fminf(mm[2][t], mm[3][t]));
      if (mt <= 0.16f) { k = t; break; }
    }
    float sf = 1.0f;                 // replicate reference's float rounding
    for (int i = 0; i < k; ++i) sf *= 0.99f;
    sfin = sf;
  }
  __syncthreads();

  if (tid < 3) {
    const int d = tid;
    const float cg = sfin * tv[d*42 + v];
    float off = 0.0f;
    #pragma unroll
    for (int k = 0; k < 8; ++k)
      off += (insKeys[(b*8+k)*3 + d] - catKeys[(b*8+k)*3 + d]) * catInflu[(b*8+k)*42 + v];
    cage [(b*42 + v)*3 + d] = cg;
    ncage[(b*42 + v)*3 + d] = cg + off;
  }
}

// ---------------------------------------------------------------------------
// Phase 2: MVC + deform. 64 points/block, 4 waves split 80 faces (20 each),
// scalar accumulators only (sW,dx,dy,dz) -> no spill. Wave 1 also emits the
// catModel passthrough copy (output 0), replacing a d2d memcpy dispatch.
// ---------------------------------------------------------------------------
__global__ __launch_bounds__(256) void k_mvc(
    const float* __restrict__ catModel, // (B,6144,3)
    const float* __restrict__ cage,     // (B,42,3)
    const float* __restrict__ ncage,    // (B,42,3)
    float* __restrict__ outCat,         // (B,6144,3) copy of catModel
    float* __restrict__ outDef)         // (B,6144,3)
{
  const int b    = blockIdx.x / 96;
  const int pblk = blockIdx.x % 96;
  const int lane = threadIdx.x & 63;
  const int w    = threadIdx.x >> 6;
  const int p    = pblk * 64 + lane;

  __shared__ float cv[126], nv[126];
  __shared__ float red[4][4][64];
  if (threadIdx.x < 126) {
    cv[threadIdx.x] = cage [b*126 + threadIdx.x];
    nv[threadIdx.x] = ncage[b*126 + threadIdx.x];
  }
  __syncthreads();

  const float qx = catModel[((size_t)b*6144 + p)*3 + 0];
  const float qy = catModel[((size_t)b*6144 + p)*3 + 1];
  const float qz = catModel[((size_t)b*6144 + p)*3 + 2];

  if (w == 1) {   // passthrough copy (output 0)
    outCat[((size_t)b*6144 + p)*3 + 0] = qx;
    outCat[((size_t)b*6144 + p)*3 + 1] = qy;
    outCat[((size_t)b*6144 + p)*3 + 2] = qz;
  }

  float sW = 0.0f, dx = 0.0f, dy = 0.0f, dz = 0.0f;

  for (int f = w*20; f < w*20 + 20; ++f) {
    const int i0 = FI[f][0], i1 = FI[f][1], i2 = FI[f][2];

    float e0x = cv[i0*3+0]-qx, e0y = cv[i0*3+1]-qy, e0z = cv[i0*3+2]-qz;
    float e1x = cv[i1*3+0]-qx, e1y = cv[i1*3+1]-qy, e1z = cv[i1*3+2]-qz;
    float e2x = cv[i2*3+0]-qx, e2y = cv[i2*3+1]-qy, e2z = cv[i2*3+2]-qz;
    float d0 = sqrtf(e0x*e0x + e0y*e0y + e0z*e0z);
    float d1 = sqrtf(e1x*e1x + e1y*e1y + e1z*e1z);
    float d2 = sqrtf(e2x*e2x + e2y*e2y + e2z*e2z);
    float r0 = 1.0f / fmaxf(d0, EPSF);
    float r1 = 1.0f / fmaxf(d1, EPSF);
    float r2 = 1.0f / fmaxf(d2, EPSF);
    float u0x = e0x*r0, u0y = e0y*r0, u0z = e0z*r0;
    float u1x = e1x*r1, u1y = e1y*r1, u1z = e1z*r1;
    float u2x = e2x*r2, u2y = e2y*r2, u2z = e2z*r2;

    float ax_ = u1x-u2x, ay_ = u1y-u2y, az_ = u1z-u2z;
    float bx_ = u2x-u0x, by_ = u2y-u0y, bz_ = u2z-u0z;
    float cx_ = u0x-u1x, cy_ = u0y-u1y, cz_ = u0z-u1z;
    float l0 = sqrtf(ax_*ax_ + ay_*ay_ + az_*az_);
    float l1 = sqrtf(bx_*bx_ + by_*by_ + bz_*bz_);
    float l2 = sqrtf(cx_*cx_ + cy_*cy_ + cz_*cz_);

    float s0 = fminf(0.5f*l0, 1.0f);
    float s1 = fminf(0.5f*l1, 1.0f);
    float s2 = fminf(0.5f*l2, 1.0f);
    float th0 = 2.0f*asinf(s0), th1 = 2.0f*asinf(s1), th2 = 2.0f*asinf(s2);
    float co0 = sqrtf(fmaxf(fmaf(-s0, s0, 1.0f), 0.0f));
    float co1 = sqrtf(fmaxf(fmaf(-s1, s1, 1.0f), 0.0f));
    float co2 = sqrtf(fmaxf(fmaf(-s2, s2, 1.0f), 0.0f));
    float st0 = 2.0f*s0*co0;   // sin(theta_k), exact identity
    float st1 = 2.0f*s1*co1;
    float st2 = 2.0f*s2*co2;

    float Sh = s0*co1*co2 + co0*s1*co2 + co0*co1*s2 - s0*s1*s2;
    float Ch = co0*co1*co2 - s0*s1*co2 - s0*co1*s2 - co0*s1*s2;
    float sh0 = Sh*fmaf(-2.0f*s0, s0, 1.0f) - Ch*st0;
    float sh1 = Sh*fmaf(-2.0f*s1, s1, 1.0f) - Ch*st1;
    float sh2 = Sh*fmaf(-2.0f*s2, s2, 1.0f) - Ch*st2;

    float c0 = 2.0f*Sh*sh0 / fmaxf(st1*st2, EPSF) - 1.0f;
    float c1 = 2.0f*Sh*sh1 / fmaxf(st2*st0, EPSF) - 1.0f;
    float c2 = 2.0f*Sh*sh2 / fmaxf(st0*st1, EPSF) - 1.0f;

    float det = u0x*(u1y*u2z - u1z*u2y)
              + u0y*(u1z*u2x - u1x*u2z)
              + u0z*(u1x*u2y - u1y*u2x);
    float sg = (det > 0.0f) ? 1.0f : ((det < 0.0f) ? -1.0f : 0.0f);
    float q0 = sg * sqrtf(fmaxf(fmaf(-c0, c0, 1.0f), 0.0f));
    float q1 = sg * sqrtf(fmaxf(fmaf(-c1, c1, 1.0f), 0.0f));
    float q2 = sg * sqrtf(fmaxf(fmaf(-c2, c2, 1.0f), 0.0f));
    bool valid = (fabsf(q0) > EPSF) && (fabsf(q1) > EPSF) && (fabsf(q2) > EPSF);

    float n0 = th0 - c1*th2 - c2*th1;
    float n1 = th1 - c2*th0 - c0*th2;
    float n2 = th2 - c0*th1 - c1*th0;
    float de0 = d0*st1*q2;
    float de1 = d1*st2*q0;
    float de2 = d2*st0*q1;
    de0 = (fabsf(de0) > EPSF) ? de0 : ((de0 >= 0.0f) ? EPSF : -EPSF);
    de1 = (fabsf(de1) > EPSF) ? de1 : ((de1 >= 0.0f) ? EPSF : -EPSF);
    de2 = (fabsf(de2) > EPSF) ? de2 : ((de2 >= 0.0f) ? EPSF : -EPSF);

    if (valid) {
      float w0 = n0/de0, w1 = n1/de1, w2 = n2/de2;
      sW += w0 + w1 + w2;
      dx = fmaf(w0, nv[i0*3+0], fmaf(w1, nv[i1*3+0], fmaf(w2, nv[i2*3+0], dx)));
      dy = fmaf(w0, nv[i0*3+1], fmaf(w1, nv[i1*3+1], fmaf(w2, nv[i2*3+1], dy)));
      dz = fmaf(w0, nv[i0*3+2], fmaf(w1, nv[i1*3+2], fmaf(w2, nv[i2*3+2], dz)));
    }
  }

  red[w][0][lane] = sW;
  red[w][1][lane] = dx;
  red[w][2][lane] = dy;
  red[w][3][lane] = dz;
  __syncthreads();

  if (w == 0) {
    float S = red[0][0][lane] + red[1][0][lane] + red[2][0][lane] + red[3][0][lane];
    float X = red[0][1][lane] + red[1][1][lane] + red[2][1][lane] + red[3][1][lane];
    float Y = red[0][2][lane] + red[1][2][lane] + red[2][2][lane] + red[3][2][lane];
    float Z = red[0][3][lane] + red[1][3][lane] + red[2][3][lane] + red[3][3][lane];
    S = (fabsf(S) > EPSF) ? S : EPSF;
    float inv = 1.0f / S;
    outDef[((size_t)b*6144 + p)*3 + 0] = X * inv;
    outDef[((size_t)b*6144 + p)*3 + 1] = Y * inv;
    outDef[((size_t)b*6144 + p)*3 + 2] = Z * inv;
  }
}

// ---------------------------------------------------------------------------
// Phase 3: chamfer mins, BOTH directions in one dispatch (1152 blocks).
// Tile pre-scaled to (-2c, |c|^2): per pair = 3 chained fma + 1 fmin.
// dir-1 cc==0 blocks also emit the insModel passthrough copy (output 1).
// ---------------------------------------------------------------------------
__global__ __launch_bounds__(256) void k_chamfer(
    const float* __restrict__ def,     // (B,6144,3)
    const float* __restrict__ ins,     // (B,6144,3)
    float*       __restrict__ outIns,  // (B,6144,3) copy of insModel
    unsigned*    __restrict__ mins)    // 2*B*6144 float-as-uint, pre-init +inf
{
  const int bx  = blockIdx.x;
  const int dir = (bx >= 576) ? 1 : 0;
  const int r   = bx - dir*576;
  const int b   = r / 144;
  const int rt  = (r % 144) / 24;
  const int cc  = r % 24;
  const int tid = threadIdx.x;

  const float* R = (dir ? ins : def) + (size_t)b * 6144 * 3;
  const float* C = (dir ? def : ins) + (size_t)b * 6144 * 3;

  const int r0 = rt*1024 + tid;
  const int r1 = r0 + 256, r2 = r0 + 512, r3 = r0 + 768;
  const float r0x = R[r0*3+0], r0y = R[r0*3+1], r0z = R[r0*3+2];
  const float r1x = R[r1*3+0], r1y = R[r1*3+1], r1z = R[r1*3+2];
  const float r2x = R[r2*3+0], r2y = R[r2*3+1], r2z = R[r2*3+2];
  const float r3x = R[r3*3+0], r3y = R[r3*3+1], r3z = R[r3*3+2];

  if (dir == 1 && cc == 0) {   // passthrough copy (output 1)
    outIns[(size_t)(b*6144 + r0)*3+0] = r0x; outIns[(size_t)(b*6144 + r0)*3+1] = r0y; outIns[(size_t)(b*6144 + r0)*3+2] = r0z;
    outIns[(size_t)(b*6144 + r1)*3+0] = r1x; outIns[(size_t)(b*6144 + r1)*3+1] = r1y; outIns[(size_t)(b*6144 + r1)*3+2] = r1z;
    outIns[(size_t)(b*6144 + r2)*3+0] = r2x; outIns[(size_t)(b*6144 + r2)*3+1] = r2y; outIns[(size_t)(b*6144 + r2)*3+2] = r2z;
    outIns[(size_t)(b*6144 + r3)*3+0] = r3x; outIns[(size_t)(b*6144 + r3)*3+1] = r3y; outIns[(size_t)(b*6144 + r3)*3+2] = r3z;
  }

  __shared__ float4 tile[256];
  {
    int c = cc*256 + tid;
    float cx = C[c*3+0], cy = C[c*3+1], cz = C[c*3+2];
    tile[tid] = make_float4(-2.0f*cx, -2.0f*cy, -2.0f*cz, cx*cx + cy*cy + cz*cz);
  }
  __syncthreads();

  float m0 = 1e30f, m1 = 1e30f, m2 = 1e30f, m3 = 1e30f;
  #pragma unroll 8
  for (int j = 0; j < 256; ++j) {
    float4 q = tile[j];
    m0 = fminf(m0, fmaf(q.x, r0x, fmaf(q.y, r0y, fmaf(q.z, r0z, q.w))));
    m1 = fminf(m1, fmaf(q.x, r1x, fmaf(q.y, r1y, fmaf(q.z, r1z, q.w))));
    m2 = fminf(m2, fmaf(q.x, r2x, fmaf(q.y, r2y, fmaf(q.z, r2z, q.w))));
    m3 = fminf(m3, fmaf(q.x, r3x, fmaf(q.y, r3y, fmaf(q.z, r3z, q.w))));
  }

  unsigned* mo = mins + dir*24576 + b*6144;
  atomicMin(&mo[r0], __float_as_uint(m0 + (r0x*r0x + r0y*r0y + r0z*r0z)));
  atomicMin(&mo[r1], __float_as_uint(m1 + (r1x*r1x + r1y*r1y + r1z*r1z)));
  atomicMin(&mo[r2], __float_as_uint(m2 + (r2x*r2x + r2y*r2y + r2z*r2z)));
  atomicMin(&mo[r3], __float_as_uint(m3 + (r3x*r3x + r3y*r3y + r3z*r3z)));
}

// ---------------------------------------------------------------------------
// Phase 4: parallel loss reduction. 96 blocks x 512 elems; pre-scaled
// atomicAdd partials into loss (zeroed by k_init).
// ---------------------------------------------------------------------------
__global__ __launch_bounds__(256) void k_loss(
    const unsigned* __restrict__ mins,  // 2*24576 entries
    float* __restrict__ loss)
{
  const int base = blockIdx.x * 512 + threadIdx.x * 2;
  float s = __uint_as_float(mins[base]) + __uint_as_float(mins[base + 1]);
  #pragma unroll
  for (int off = 32; off; off >>= 1) s += __shfl_xor(s, off, 64);
  __shared__ float red[4];
  if ((threadIdx.x & 63) == 0) red[threadIdx.x >> 6] = s;
  __syncthreads();
  if (threadIdx.x == 0)
    atomicAdd(loss, (red[0] + red[1] + red[2] + red[3]) * (1.0f / 24576.0f));
}

// ---------------------------------------------------------------------------
extern "C" void kernel_launch(void* const* d_in, const int* in_sizes, int n_in,
                              void* d_out, int out_size, void* d_ws, size_t ws_size,
                              hipStream_t stream) {
  const float* catModel = (const float*)d_in[0];  // (4,6144,3)
  const float* catKeys  = (const float*)d_in[1];  // (4,8,3)
  const float* catInflu = (const float*)d_in[2];  // (4,8,42)
  const float* insKeys  = (const float*)d_in[3];  // (4,8,3)
  const float* insModel = (const float*)d_in[4];  // (4,6144,3)
  const float* tv       = (const float*)d_in[5];  // (1,3,42)
  // d_in[6] = template_faces, baked in as FI[][]

  float* out = (float*)d_out;       // [catModel | insModel | deformed | loss]
  float* ws  = (float*)d_ws;
  float*    cage  = ws;                       // 504 floats (pad to 512)
  float*    ncage = ws + 512;                 // 504 floats
  unsigned* mins  = (unsigned*)(ws + 1024);   // 49152 uints

  k_init<<<192, 256, 0, stream>>>(mins, 49152, out + 221184);
  k_cage<<<168, 256, 0, stream>>>(catModel, tv, catKeys, insKeys, catInflu, cage, ncage);
  k_mvc <<<384, 256, 0, stream>>>(catModel, cage, ncage, out, out + 147456);
  k_chamfer<<<1152, 256, 0, stream>>>(out + 147456, insModel, out + 73728, mins);
  k_loss<<<96, 256, 0, stream>>>(mins, out + 221184);
}

// Round 5
// 161.172 us; speedup vs baseline: 2.1569x; 1.0749x over previous
//
#include <hip/hip_runtime.h>
#include <hip/hip_bf16.h>
#include <math.h>

#define EPSF 1e-8f

// Icosphere div-1 connectivity, deterministically produced by _icosphere_div1().
static constexpr int FI[80][3] = {
  {0,12,14},{11,13,12},{5,14,13},{12,13,14},
  {0,14,16},{5,15,14},{1,16,15},{14,15,16},
  {0,16,18},{1,17,16},{7,18,17},{16,17,18},
  {0,18,20},{7,19,18},{10,20,19},{18,19,20},
  {0,20,12},{10,21,20},{11,12,21},{20,21,12},
  {1,15,23},{5,22,15},{9,23,22},{15,22,23},
  {5,13,25},{11,24,13},{4,25,24},{13,24,25},
  {11,21,27},{10,26,21},{2,27,26},{21,26,27},
  {10,19,29},{7,28,19},{6,29,28},{19,28,29},
  {7,17,31},{1,30,17},{8,31,30},{17,30,31},
  {3,32,34},{9,33,32},{4,34,33},{32,33,34},
  {3,34,36},{4,35,34},{2,36,35},{34,35,36},
  {3,36,38},{2,37,36},{6,38,37},{36,37,38},
  {3,38,40},{6,39,38},{8,40,39},{38,39,40},
  {3,40,32},{8,41,40},{9,32,41},{40,41,32},
  {4,33,25},{9,22,33},{5,25,22},{33,22,25},
  {2,35,27},{4,24,35},{11,27,24},{35,24,27},
  {6,37,29},{2,26,37},{10,29,26},{37,26,29},
  {8,39,31},{6,28,39},{7,31,28},{39,28,31},
  {9,41,23},{8,30,41},{1,23,30},{41,30,23}
};

// ---------------------------------------------------------------------------
// Phase 0: init mins to +inf, loss slot to 0.
// ---------------------------------------------------------------------------
__global__ __launch_bounds__(256) void k_init(unsigned* __restrict__ p, int n,
                                              float* __restrict__ loss) {
  int i = blockIdx.x * 256 + threadIdx.x;
  if (i < n) p[i] = 0x7F800000u;  // +inf
  if (i == 0) loss[0] = 0.0f;
}

// ---------------------------------------------------------------------------
// Phase 1: cage shrink (round-3 verified version). s_final = 0.99^k,
// k = first t in [0,100) with min-dist^2(0.99^t) <= 0.16.
// ---------------------------------------------------------------------------
__global__ __launch_bounds__(256) void k_cage(
    const float* __restrict__ catModel,   // (B,6144,3)
    const float* __restrict__ tv,         // (1,3,42)
    const float* __restrict__ catKeys,    // (B,8,3)
    const float* __restrict__ insKeys,    // (B,8,3)
    const float* __restrict__ catInflu,   // (B,8,42)
    float* __restrict__ cage,             // (B,42,3) out
    float* __restrict__ ncage)            // (B,42,3) out
{
  const int b = blockIdx.x / 42, v = blockIdx.x % 42;
  const int tid = threadIdx.x;
  const int lane = tid & 63, w = tid >> 6;
  const float c0x = tv[v], c0y = tv[42 + v], c0z = tv[84 + v];
  const float a = c0x*c0x + c0y*c0y + c0z*c0z;

  float pb2[24], pc[24];
  const float* P = catModel + (size_t)b * 6144 * 3;
  #pragma unroll
  for (int j = 0; j < 24; ++j) {
    int n = tid + j * 256;
    float px = P[n*3+0], py = P[n*3+1], pz = P[n*3+2];
    pb2[j] = -2.0f * (c0x*px + c0y*py + c0z*pz);
    pc[j]  = px*px + py*py + pz*pz;
  }

  __shared__ float mm[4][100];
  __shared__ float sfin;

  float s = 1.0f;
  for (int t = 0; t < 100; ++t) {
    float ma = 1e30f, mb = 1e30f, mc = 1e30f, md = 1e30f;
    #pragma unroll
    for (int j = 0; j < 24; j += 4) {        // 4 independent min chains
      ma = fminf(ma, fmaf(fmaf(a, s, pb2[j+0]), s, pc[j+0]));
      mb = fminf(mb, fmaf(fmaf(a, s, pb2[j+1]), s, pc[j+1]));
      mc = fminf(mc, fmaf(fmaf(a, s, pb2[j+2]), s, pc[j+2]));
      md = fminf(md, fmaf(fmaf(a, s, pb2[j+3]), s, pc[j+3]));
    }
    float m = fminf(fminf(ma, mb), fminf(mc, md));
    #pragma unroll
    for (int off = 32; off; off >>= 1)
      m = fminf(m, __shfl_xor(m, off, 64));
    if (lane == 0) mm[w][t] = m;
    s *= 0.99f;
  }
  __syncthreads();

  if (tid == 0) {
    int k = 100;
    for (int t = 0; t < 100; ++t) {
      float mt = fminf(fminf(mm[0][t], mm[1][t]), fminf(mm[2][t], mm[3][t]));
      if (mt <= 0.16f) { k = t; break; }
    }
    float sf = 1.0f;                 // replicate reference's float rounding
    for (int i = 0; i < k; ++i) sf *= 0.99f;
    sfin = sf;
  }
  __syncthreads();

  if (tid < 3) {
    const int d = tid;
    const float cg = sfin * tv[d*42 + v];
    float off = 0.0f;
    #pragma unroll
    for (int k = 0; k < 8; ++k)
      off += (insKeys[(b*8+k)*3 + d] - catKeys[(b*8+k)*3 + d]) * catInflu[(b*8+k)*42 + v];
    cage [(b*42 + v)*3 + d] = cg;
    ncage[(b*42 + v)*3 + d] = cg + off;
  }
}

// ---------------------------------------------------------------------------
// Phase 2: MVC + deform. Retile: 16 points/block x 16 face-slices of 5 faces
// (grid B*384, occupancy cap 75%). Math identical to round-3 (libm asinf,
// sqrtf, exact divisions, reference op order) — the verified-correct path.
// ---------------------------------------------------------------------------
__global__ __launch_bounds__(256) void k_mvc(
    const float* __restrict__ catModel, // (B,6144,3)
    const float* __restrict__ cage,     // (B,42,3)
    const float* __restrict__ ncage,    // (B,42,3)
    float* __restrict__ outCat,         // (B,6144,3) copy of catModel
    float* __restrict__ outDef)         // (B,6144,3)
{
  const int b    = blockIdx.x / 384;
  const int pblk = blockIdx.x % 384;
  const int lane = threadIdx.x & 63;
  const int w    = threadIdx.x >> 6;
  const int pt   = lane & 15;
  const int sub  = lane >> 4;
  const int slice = w*4 + sub;
  const int p    = pblk * 16 + pt;

  __shared__ float cv[126], nv[126];
  __shared__ unsigned sF[80];
  __shared__ float red[4][4][16];
  if (threadIdx.x < 126) {
    cv[threadIdx.x] = cage [b*126 + threadIdx.x];
    nv[threadIdx.x] = ncage[b*126 + threadIdx.x];
  }
  if (threadIdx.x < 80) {
    sF[threadIdx.x] = (unsigned)FI[threadIdx.x][0]
                    | ((unsigned)FI[threadIdx.x][1] << 8)
                    | ((unsigned)FI[threadIdx.x][2] << 16);
  }
  __syncthreads();

  const float qx = catModel[((size_t)b*6144 + p)*3 + 0];
  const float qy = catModel[((size_t)b*6144 + p)*3 + 1];
  const float qz = catModel[((size_t)b*6144 + p)*3 + 2];

  if (w == 1 && sub == 0) {   // passthrough copy (output 0)
    outCat[((size_t)b*6144 + p)*3 + 0] = qx;
    outCat[((size_t)b*6144 + p)*3 + 1] = qy;
    outCat[((size_t)b*6144 + p)*3 + 2] = qz;
  }

  float sW = 0.0f, dx = 0.0f, dy = 0.0f, dz = 0.0f;

  for (int ff = 0; ff < 5; ++ff) {
    const unsigned pk = sF[slice*5 + ff];
    const int i0 = pk & 255, i1 = (pk >> 8) & 255, i2 = pk >> 16;

    float e0x = cv[i0*3+0]-qx, e0y = cv[i0*3+1]-qy, e0z = cv[i0*3+2]-qz;
    float e1x = cv[i1*3+0]-qx, e1y = cv[i1*3+1]-qy, e1z = cv[i1*3+2]-qz;
    float e2x = cv[i2*3+0]-qx, e2y = cv[i2*3+1]-qy, e2z = cv[i2*3+2]-qz;
    float d0 = sqrtf(e0x*e0x + e0y*e0y + e0z*e0z);
    float d1 = sqrtf(e1x*e1x + e1y*e1y + e1z*e1z);
    float d2 = sqrtf(e2x*e2x + e2y*e2y + e2z*e2z);
    float r0 = 1.0f / fmaxf(d0, EPSF);
    float r1 = 1.0f / fmaxf(d1, EPSF);
    float r2 = 1.0f / fmaxf(d2, EPSF);
    float u0x = e0x*r0, u0y = e0y*r0, u0z = e0z*r0;
    float u1x = e1x*r1, u1y = e1y*r1, u1z = e1z*r1;
    float u2x = e2x*r2, u2y = e2y*r2, u2z = e2z*r2;

    float ax_ = u1x-u2x, ay_ = u1y-u2y, az_ = u1z-u2z;
    float bx_ = u2x-u0x, by_ = u2y-u0y, bz_ = u2z-u0z;
    float cx_ = u0x-u1x, cy_ = u0y-u1y, cz_ = u0z-u1z;
    float l0 = sqrtf(ax_*ax_ + ay_*ay_ + az_*az_);
    float l1 = sqrtf(bx_*bx_ + by_*by_ + bz_*bz_);
    float l2 = sqrtf(cx_*cx_ + cy_*cy_ + cz_*cz_);

    float s0 = fminf(0.5f*l0, 1.0f);
    float s1 = fminf(0.5f*l1, 1.0f);
    float s2 = fminf(0.5f*l2, 1.0f);
    float th0 = 2.0f*asinf(s0), th1 = 2.0f*asinf(s1), th2 = 2.0f*asinf(s2);
    float co0 = sqrtf(fmaxf(fmaf(-s0, s0, 1.0f), 0.0f));
    float co1 = sqrtf(fmaxf(fmaf(-s1, s1, 1.0f), 0.0f));
    float co2 = sqrtf(fmaxf(fmaf(-s2, s2, 1.0f), 0.0f));
    float st0 = 2.0f*s0*co0;   // sin(theta_k), exact identity
    float st1 = 2.0f*s1*co1;
    float st2 = 2.0f*s2*co2;

    // sin/cos of h = a0+a1+a2 (a_k = asin(s_k)) by angle-sum expansion
    float Sh = s0*co1*co2 + co0*s1*co2 + co0*co1*s2 - s0*s1*s2;
    float Ch = co0*co1*co2 - s0*s1*co2 - s0*co1*s2 - co0*s1*s2;
    // sin(h - theta_k) = Sh*cos(2ak) - Ch*sin(2ak)
    float sh0 = Sh*fmaf(-2.0f*s0, s0, 1.0f) - Ch*st0;
    float sh1 = Sh*fmaf(-2.0f*s1, s1, 1.0f) - Ch*st1;
    float sh2 = Sh*fmaf(-2.0f*s2, s2, 1.0f) - Ch*st2;

    float c0 = 2.0f*Sh*sh0 / fmaxf(st1*st2, EPSF) - 1.0f;
    float c1 = 2.0f*Sh*sh1 / fmaxf(st2*st0, EPSF) - 1.0f;
    float c2 = 2.0f*Sh*sh2 / fmaxf(st0*st1, EPSF) - 1.0f;

    float det = u0x*(u1y*u2z - u1z*u2y)
              + u0y*(u1z*u2x - u1x*u2z)
              + u0z*(u1x*u2y - u1y*u2x);
    float sg = (det > 0.0f) ? 1.0f : ((det < 0.0f) ? -1.0f : 0.0f);
    float q0 = sg * sqrtf(fmaxf(fmaf(-c0, c0, 1.0f), 0.0f));
    float q1 = sg * sqrtf(fmaxf(fmaf(-c1, c1, 1.0f), 0.0f));
    float q2 = sg * sqrtf(fmaxf(fmaf(-c2, c2, 1.0f), 0.0f));
    bool valid = (fabsf(q0) > EPSF) && (fabsf(q1) > EPSF) && (fabsf(q2) > EPSF);

    float n0 = th0 - c1*th2 - c2*th1;
    float n1 = th1 - c2*th0 - c0*th2;
    float n2 = th2 - c0*th1 - c1*th0;
    float de0 = d0*st1*q2;
    float de1 = d1*st2*q0;
    float de2 = d2*st0*q1;
    de0 = (fabsf(de0) > EPSF) ? de0 : ((de0 >= 0.0f) ? EPSF : -EPSF);
    de1 = (fabsf(de1) > EPSF) ? de1 : ((de1 >= 0.0f) ? EPSF : -EPSF);
    de2 = (fabsf(de2) > EPSF) ? de2 : ((de2 >= 0.0f) ? EPSF : -EPSF);

    if (valid) {
      float w0 = n0/de0, w1 = n1/de1, w2 = n2/de2;
      sW += w0 + w1 + w2;
      dx = fmaf(w0, nv[i0*3+0], fmaf(w1, nv[i1*3+0], fmaf(w2, nv[i2*3+0], dx)));
      dy = fmaf(w0, nv[i0*3+1], fmaf(w1, nv[i1*3+1], fmaf(w2, nv[i2*3+1], dy)));
      dz = fmaf(w0, nv[i0*3+2], fmaf(w1, nv[i1*3+2], fmaf(w2, nv[i2*3+2], dz)));
    }
  }

  // reduce over 4 sub-slices within the wave (lanes pt, pt+16, pt+32, pt+48)
  sW += __shfl_xor(sW, 16, 64); dx += __shfl_xor(dx, 16, 64);
  dy += __shfl_xor(dy, 16, 64); dz += __shfl_xor(dz, 16, 64);
  sW += __shfl_xor(sW, 32, 64); dx += __shfl_xor(dx, 32, 64);
  dy += __shfl_xor(dy, 32, 64); dz += __shfl_xor(dz, 32, 64);

  if (sub == 0) {
    red[w][0][pt] = sW; red[w][1][pt] = dx;
    red[w][2][pt] = dy; red[w][3][pt] = dz;
  }
  __syncthreads();

  if (w == 0 && sub == 0) {
    float S = red[0][0][pt] + red[1][0][pt] + red[2][0][pt] + red[3][0][pt];
    float X = red[0][1][pt] + red[1][1][pt] + red[2][1][pt] + red[3][1][pt];
    float Y = red[0][2][pt] + red[1][2][pt] + red[2][2][pt] + red[3][2][pt];
    float Z = red[0][3][pt] + red[1][3][pt] + red[2][3][pt] + red[3][3][pt];
    S = (fabsf(S) > EPSF) ? S : EPSF;
    float inv = 1.0f / S;
    outDef[((size_t)b*6144 + p)*3 + 0] = X * inv;
    outDef[((size_t)b*6144 + p)*3 + 1] = Y * inv;
    outDef[((size_t)b*6144 + p)*3 + 2] = Z * inv;
  }
}

// ---------------------------------------------------------------------------
// Phase 3: chamfer mins, BOTH directions in one dispatch (1152 blocks).
// Tile pre-scaled to (-2c, |c|^2): per pair = 3 chained fma + 1 fmin.
// ---------------------------------------------------------------------------
__global__ __launch_bounds__(256) void k_chamfer(
    const float* __restrict__ def,     // (B,6144,3)
    const float* __restrict__ ins,     // (B,6144,3)
    float*       __restrict__ outIns,  // (B,6144,3) copy of insModel
    unsigned*    __restrict__ mins)    // 2*B*6144 float-as-uint, pre-init +inf
{
  const int bx  = blockIdx.x;
  const int dir = (bx >= 576) ? 1 : 0;
  const int r   = bx - dir*576;
  const int b   = r / 144;
  const int rt  = (r % 144) / 24;
  const int cc  = r % 24;
  const int tid = threadIdx.x;

  const float* R = (dir ? ins : def) + (size_t)b * 6144 * 3;
  const float* C = (dir ? def : ins) + (size_t)b * 6144 * 3;

  const int r0 = rt*1024 + tid;
  const int r1 = r0 + 256, r2 = r0 + 512, r3 = r0 + 768;
  const float r0x = R[r0*3+0], r0y = R[r0*3+1], r0z = R[r0*3+2];
  const float r1x = R[r1*3+0], r1y = R[r1*3+1], r1z = R[r1*3+2];
  const float r2x = R[r2*3+0], r2y = R[r2*3+1], r2z = R[r2*3+2];
  const float r3x = R[r3*3+0], r3y = R[r3*3+1], r3z = R[r3*3+2];

  if (dir == 1 && cc == 0) {   // passthrough copy (output 1)
    outIns[(size_t)(b*6144 + r0)*3+0] = r0x; outIns[(size_t)(b*6144 + r0)*3+1] = r0y; outIns[(size_t)(b*6144 + r0)*3+2] = r0z;
    outIns[(size_t)(b*6144 + r1)*3+0] = r1x; outIns[(size_t)(b*6144 + r1)*3+1] = r1y; outIns[(size_t)(b*6144 + r1)*3+2] = r1z;
    outIns[(size_t)(b*6144 + r2)*3+0] = r2x; outIns[(size_t)(b*6144 + r2)*3+1] = r2y; outIns[(size_t)(b*6144 + r2)*3+2] = r2z;
    outIns[(size_t)(b*6144 + r3)*3+0] = r3x; outIns[(size_t)(b*6144 + r3)*3+1] = r3y; outIns[(size_t)(b*6144 + r3)*3+2] = r3z;
  }

  __shared__ float4 tile[256];
  {
    int c = cc*256 + tid;
    float cx = C[c*3+0], cy = C[c*3+1], cz = C[c*3+2];
    tile[tid] = make_float4(-2.0f*cx, -2.0f*cy, -2.0f*cz, cx*cx + cy*cy + cz*cz);
  }
  __syncthreads();

  float m0 = 1e30f, m1 = 1e30f, m2 = 1e30f, m3 = 1e30f;
  #pragma unroll 8
  for (int j = 0; j < 256; ++j) {
    float4 q = tile[j];
    m0 = fminf(m0, fmaf(q.x, r0x, fmaf(q.y, r0y, fmaf(q.z, r0z, q.w))));
    m1 = fminf(m1, fmaf(q.x, r1x, fmaf(q.y, r1y, fmaf(q.z, r1z, q.w))));
    m2 = fminf(m2, fmaf(q.x, r2x, fmaf(q.y, r2y, fmaf(q.z, r2z, q.w))));
    m3 = fminf(m3, fmaf(q.x, r3x, fmaf(q.y, r3y, fmaf(q.z, r3z, q.w))));
  }

  unsigned* mo = mins + dir*24576 + b*6144;
  atomicMin(&mo[r0], __float_as_uint(m0 + (r0x*r0x + r0y*r0y + r0z*r0z)));
  atomicMin(&mo[r1], __float_as_uint(m1 + (r1x*r1x + r1y*r1y + r1z*r1z)));
  atomicMin(&mo[r2], __float_as_uint(m2 + (r2x*r2x + r2y*r2y + r2z*r2z)));
  atomicMin(&mo[r3], __float_as_uint(m3 + (r3x*r3x + r3y*r3y + r3z*r3z)));
}

// ---------------------------------------------------------------------------
// Phase 4: parallel loss reduction. 96 blocks x 512 elems; pre-scaled
// atomicAdd partials into loss (zeroed by k_init).
// ---------------------------------------------------------------------------
__global__ __launch_bounds__(256) void k_loss(
    const unsigned* __restrict__ mins,  // 2*24576 entries
    float* __restrict__ loss)
{
  const int base = blockIdx.x * 512 + threadIdx.x * 2;
  float s = __uint_as_float(mins[base]) + __uint_as_float(mins[base + 1]);
  #pragma unroll
  for (int off = 32; off; off >>= 1) s += __shfl_xor(s, off, 64);
  __shared__ float red[4];
  if ((threadIdx.x & 63) == 0) red[threadIdx.x >> 6] = s;
  __syncthreads();
  if (threadIdx.x == 0)
    atomicAdd(loss, (red[0] + red[1] + red[2] + red[3]) * (1.0f / 24576.0f));
}

// ---------------------------------------------------------------------------
extern "C" void kernel_launch(void* const* d_in, const int* in_sizes, int n_in,
                              void* d_out, int out_size, void* d_ws, size_t ws_size,
                              hipStream_t stream) {
  const float* catModel = (const float*)d_in[0];  // (4,6144,3)
  const float* catKeys  = (const float*)d_in[1];  // (4,8,3)
  const float* catInflu = (const float*)d_in[2];  // (4,8,42)
  const float* insKeys  = (const float*)d_in[3];  // (4,8,3)
  const float* insModel = (const float*)d_in[4];  // (4,6144,3)
  const float* tv       = (const float*)d_in[5];  // (1,3,42)
  // d_in[6] = template_faces, baked in as FI[][]

  float* out = (float*)d_out;       // [catModel | insModel | deformed | loss]
  float* ws  = (float*)d_ws;
  float*    cage  = ws;                       // 504 floats (pad to 512)
  float*    ncage = ws + 512;                 // 504 floats
  unsigned* mins  = (unsigned*)(ws + 1024);   // 49152 uints

  k_init<<<192, 256, 0, stream>>>(mins, 49152, out + 221184);
  k_cage<<<168, 256, 0, stream>>>(catModel, tv, catKeys, insKeys, catInflu, cage, ncage);
  k_mvc <<<1536, 256, 0, stream>>>(catModel, cage, ncage, out, out + 147456);
  k_chamfer<<<1152, 256, 0, stream>>>(out + 147456, insModel, out + 73728, mins);
  k_loss<<<96, 256, 0, stream>>>(mins, out + 221184);
}

// Round 6
// 137.555 us; speedup vs baseline: 2.5272x; 1.1717x over previous
//
#include <hip/hip_runtime.h>
#include <hip/hip_bf16.h>
#include <math.h>

#define EPSF 1e-8f

// Icosphere div-1 connectivity, deterministically produced by _icosphere_div1().
static constexpr int FI[80][3] = {
  {0,12,14},{11,13,12},{5,14,13},{12,13,14},
  {0,14,16},{5,15,14},{1,16,15},{14,15,16},
  {0,16,18},{1,17,16},{7,18,17},{16,17,18},
  {0,18,20},{7,19,18},{10,20,19},{18,19,20},
  {0,20,12},{10,21,20},{11,12,21},{20,21,12},
  {1,15,23},{5,22,15},{9,23,22},{15,22,23},
  {5,13,25},{11,24,13},{4,25,24},{13,24,25},
  {11,21,27},{10,26,21},{2,27,26},{21,26,27},
  {10,19,29},{7,28,19},{6,29,28},{19,28,29},
  {7,17,31},{1,30,17},{8,31,30},{17,30,31},
  {3,32,34},{9,33,32},{4,34,33},{32,33,34},
  {3,34,36},{4,35,34},{2,36,35},{34,35,36},
  {3,36,38},{2,37,36},{6,38,37},{36,37,38},
  {3,38,40},{6,39,38},{8,40,39},{38,39,40},
  {3,40,32},{8,41,40},{9,32,41},{40,41,32},
  {4,33,25},{9,22,33},{5,25,22},{33,22,25},
  {2,35,27},{4,24,35},{11,27,24},{35,24,27},
  {6,37,29},{2,26,37},{10,29,26},{37,26,29},
  {8,39,31},{6,28,39},{7,31,28},{39,28,31},
  {9,41,23},{8,30,41},{1,23,30},{41,30,23}
};

// ---------------------------------------------------------------------------
// Phase 0: init mins to +inf, loss slot to 0.
// ---------------------------------------------------------------------------
__global__ __launch_bounds__(256) void k_init(unsigned* __restrict__ p, int n,
                                              float* __restrict__ loss) {
  int i = blockIdx.x * 256 + threadIdx.x;
  if (i < n) p[i] = 0x7F800000u;  // +inf
  if (i == 0) loss[0] = 0.0f;
}

// ---------------------------------------------------------------------------
// Phase 1: cage shrink. Same arithmetic as the verified round-3/5 version
// (dd = fmaf(fmaf(a,s,pb2),s,pc), s *= 0.99f sequence), but the cross-lane
// reduce is hoisted OUT of the 100-iter loop: each thread records tmin =
// first t where its own 12-point min <= 0.16; k = min over threads (exact:
// min of first-triggers == first trigger of global min). Per-wave early
// exit once all lanes have triggered. 512 thr/block -> 2 waves/SIMD.
// ---------------------------------------------------------------------------
__global__ __launch_bounds__(512) void k_cage(
    const float* __restrict__ catModel,   // (B,6144,3)
    const float* __restrict__ tv,         // (1,3,42)
    const float* __restrict__ catKeys,    // (B,8,3)
    const float* __restrict__ insKeys,    // (B,8,3)
    const float* __restrict__ catInflu,   // (B,8,42)
    float* __restrict__ cage,             // (B,42,3) out
    float* __restrict__ ncage)            // (B,42,3) out
{
  const int b = blockIdx.x / 42, v = blockIdx.x % 42;
  const int tid = threadIdx.x;
  const int lane = tid & 63, w = tid >> 6;   // 8 waves
  const float c0x = tv[v], c0y = tv[42 + v], c0z = tv[84 + v];
  const float a = c0x*c0x + c0y*c0y + c0z*c0z;

  float pb2[12], pc[12];
  const float* P = catModel + (size_t)b * 6144 * 3;
  #pragma unroll
  for (int j = 0; j < 12; ++j) {
    int n = tid + j * 512;
    float px = P[n*3+0], py = P[n*3+1], pz = P[n*3+2];
    pb2[j] = -2.0f * (c0x*px + c0y*py + c0z*pz);
    pc[j]  = px*px + py*py + pz*pz;
  }

  __shared__ int mm[8];
  __shared__ float sfin;

  int tmin = 1000;
  float s = 1.0f;
  for (int t = 0; t < 100; ++t) {
    float ma = 1e30f, mb = 1e30f, mc = 1e30f, md = 1e30f;
    #pragma unroll
    for (int j = 0; j < 12; j += 4) {        // 4 independent min chains
      ma = fminf(ma, fmaf(fmaf(a, s, pb2[j+0]), s, pc[j+0]));
      mb = fminf(mb, fmaf(fmaf(a, s, pb2[j+1]), s, pc[j+1]));
      mc = fminf(mc, fmaf(fmaf(a, s, pb2[j+2]), s, pc[j+2]));
      md = fminf(md, fmaf(fmaf(a, s, pb2[j+3]), s, pc[j+3]));
    }
    float m = fminf(fminf(ma, mb), fminf(mc, md));
    if (m <= 0.16f && tmin == 1000) tmin = t;    // first trigger for this thread
    if (__all(tmin != 1000)) break;              // whole wave done -> exit
    s *= 0.99f;
  }

  #pragma unroll
  for (int off = 32; off; off >>= 1)
    tmin = min(tmin, __shfl_xor(tmin, off, 64));
  if (lane == 0) mm[w] = tmin;
  __syncthreads();

  if (tid == 0) {
    int k = mm[0];
    #pragma unroll
    for (int i = 1; i < 8; ++i) k = min(k, mm[i]);
    if (k > 100) k = 100;
    float sf = 1.0f;                 // replicate reference's float rounding
    for (int i = 0; i < k; ++i) sf *= 0.99f;
    sfin = sf;
  }
  __syncthreads();

  if (tid < 3) {
    const int d = tid;
    const float cg = sfin * tv[d*42 + v];
    float off = 0.0f;
    #pragma unroll
    for (int k = 0; k < 8; ++k)
      off += (insKeys[(b*8+k)*3 + d] - catKeys[(b*8+k)*3 + d]) * catInflu[(b*8+k)*42 + v];
    cage [(b*42 + v)*3 + d] = cg;
    ncage[(b*42 + v)*3 + d] = cg + off;
  }
}

// ---------------------------------------------------------------------------
// Phase 2: MVC + deform. 16 points/block x 16 face-slices of 5 faces
// (grid B*384). Math identical to round-3 (libm asinf, sqrtf, exact
// divisions, reference op order) — the verified-correct path.
// ---------------------------------------------------------------------------
__global__ __launch_bounds__(256) void k_mvc(
    const float* __restrict__ catModel, // (B,6144,3)
    const float* __restrict__ cage,     // (B,42,3)
    const float* __restrict__ ncage,    // (B,42,3)
    float* __restrict__ outCat,         // (B,6144,3) copy of catModel
    float* __restrict__ outDef)         // (B,6144,3)
{
  const int b    = blockIdx.x / 384;
  const int pblk = blockIdx.x % 384;
  const int lane = threadIdx.x & 63;
  const int w    = threadIdx.x >> 6;
  const int pt   = lane & 15;
  const int sub  = lane >> 4;
  const int slice = w*4 + sub;
  const int p    = pblk * 16 + pt;

  __shared__ float cv[126], nv[126];
  __shared__ unsigned sF[80];
  __shared__ float red[4][4][16];
  if (threadIdx.x < 126) {
    cv[threadIdx.x] = cage [b*126 + threadIdx.x];
    nv[threadIdx.x] = ncage[b*126 + threadIdx.x];
  }
  if (threadIdx.x < 80) {
    sF[threadIdx.x] = (unsigned)FI[threadIdx.x][0]
                    | ((unsigned)FI[threadIdx.x][1] << 8)
                    | ((unsigned)FI[threadIdx.x][2] << 16);
  }
  __syncthreads();

  const float qx = catModel[((size_t)b*6144 + p)*3 + 0];
  const float qy = catModel[((size_t)b*6144 + p)*3 + 1];
  const float qz = catModel[((size_t)b*6144 + p)*3 + 2];

  if (w == 1 && sub == 0) {   // passthrough copy (output 0)
    outCat[((size_t)b*6144 + p)*3 + 0] = qx;
    outCat[((size_t)b*6144 + p)*3 + 1] = qy;
    outCat[((size_t)b*6144 + p)*3 + 2] = qz;
  }

  float sW = 0.0f, dx = 0.0f, dy = 0.0f, dz = 0.0f;

  for (int ff = 0; ff < 5; ++ff) {
    const unsigned pk = sF[slice*5 + ff];
    const int i0 = pk & 255, i1 = (pk >> 8) & 255, i2 = pk >> 16;

    float e0x = cv[i0*3+0]-qx, e0y = cv[i0*3+1]-qy, e0z = cv[i0*3+2]-qz;
    float e1x = cv[i1*3+0]-qx, e1y = cv[i1*3+1]-qy, e1z = cv[i1*3+2]-qz;
    float e2x = cv[i2*3+0]-qx, e2y = cv[i2*3+1]-qy, e2z = cv[i2*3+2]-qz;
    float d0 = sqrtf(e0x*e0x + e0y*e0y + e0z*e0z);
    float d1 = sqrtf(e1x*e1x + e1y*e1y + e1z*e1z);
    float d2 = sqrtf(e2x*e2x + e2y*e2y + e2z*e2z);
    float r0 = 1.0f / fmaxf(d0, EPSF);
    float r1 = 1.0f / fmaxf(d1, EPSF);
    float r2 = 1.0f / fmaxf(d2, EPSF);
    float u0x = e0x*r0, u0y = e0y*r0, u0z = e0z*r0;
    float u1x = e1x*r1, u1y = e1y*r1, u1z = e1z*r1;
    float u2x = e2x*r2, u2y = e2y*r2, u2z = e2z*r2;

    float ax_ = u1x-u2x, ay_ = u1y-u2y, az_ = u1z-u2z;
    float bx_ = u2x-u0x, by_ = u2y-u0y, bz_ = u2z-u0z;
    float cx_ = u0x-u1x, cy_ = u0y-u1y, cz_ = u0z-u1z;
    float l0 = sqrtf(ax_*ax_ + ay_*ay_ + az_*az_);
    float l1 = sqrtf(bx_*bx_ + by_*by_ + bz_*bz_);
    float l2 = sqrtf(cx_*cx_ + cy_*cy_ + cz_*cz_);

    float s0 = fminf(0.5f*l0, 1.0f);
    float s1 = fminf(0.5f*l1, 1.0f);
    float s2 = fminf(0.5f*l2, 1.0f);
    float th0 = 2.0f*asinf(s0), th1 = 2.0f*asinf(s1), th2 = 2.0f*asinf(s2);
    float co0 = sqrtf(fmaxf(fmaf(-s0, s0, 1.0f), 0.0f));
    float co1 = sqrtf(fmaxf(fmaf(-s1, s1, 1.0f), 0.0f));
    float co2 = sqrtf(fmaxf(fmaf(-s2, s2, 1.0f), 0.0f));
    float st0 = 2.0f*s0*co0;   // sin(theta_k), exact identity
    float st1 = 2.0f*s1*co1;
    float st2 = 2.0f*s2*co2;

    // sin/cos of h = a0+a1+a2 (a_k = asin(s_k)) by angle-sum expansion
    float Sh = s0*co1*co2 + co0*s1*co2 + co0*co1*s2 - s0*s1*s2;
    float Ch = co0*co1*co2 - s0*s1*co2 - s0*co1*s2 - co0*s1*s2;
    // sin(h - theta_k) = Sh*cos(2ak) - Ch*sin(2ak)
    float sh0 = Sh*fmaf(-2.0f*s0, s0, 1.0f) - Ch*st0;
    float sh1 = Sh*fmaf(-2.0f*s1, s1, 1.0f) - Ch*st1;
    float sh2 = Sh*fmaf(-2.0f*s2, s2, 1.0f) - Ch*st2;

    float c0 = 2.0f*Sh*sh0 / fmaxf(st1*st2, EPSF) - 1.0f;
    float c1 = 2.0f*Sh*sh1 / fmaxf(st2*st0, EPSF) - 1.0f;
    float c2 = 2.0f*Sh*sh2 / fmaxf(st0*st1, EPSF) - 1.0f;

    float det = u0x*(u1y*u2z - u1z*u2y)
              + u0y*(u1z*u2x - u1x*u2z)
              + u0z*(u1x*u2y - u1y*u2x);
    float sg = (det > 0.0f) ? 1.0f : ((det < 0.0f) ? -1.0f : 0.0f);
    float q0 = sg * sqrtf(fmaxf(fmaf(-c0, c0, 1.0f), 0.0f));
    float q1 = sg * sqrtf(fmaxf(fmaf(-c1, c1, 1.0f), 0.0f));
    float q2 = sg * sqrtf(fmaxf(fmaf(-c2, c2, 1.0f), 0.0f));
    bool valid = (fabsf(q0) > EPSF) && (fabsf(q1) > EPSF) && (fabsf(q2) > EPSF);

    float n0 = th0 - c1*th2 - c2*th1;
    float n1 = th1 - c2*th0 - c0*th2;
    float n2 = th2 - c0*th1 - c1*th0;
    float de0 = d0*st1*q2;
    float de1 = d1*st2*q0;
    float de2 = d2*st0*q1;
    de0 = (fabsf(de0) > EPSF) ? de0 : ((de0 >= 0.0f) ? EPSF : -EPSF);
    de1 = (fabsf(de1) > EPSF) ? de1 : ((de1 >= 0.0f) ? EPSF : -EPSF);
    de2 = (fabsf(de2) > EPSF) ? de2 : ((de2 >= 0.0f) ? EPSF : -EPSF);

    if (valid) {
      float w0 = n0/de0, w1 = n1/de1, w2 = n2/de2;
      sW += w0 + w1 + w2;
      dx = fmaf(w0, nv[i0*3+0], fmaf(w1, nv[i1*3+0], fmaf(w2, nv[i2*3+0], dx)));
      dy = fmaf(w0, nv[i0*3+1], fmaf(w1, nv[i1*3+1], fmaf(w2, nv[i2*3+1], dy)));
      dz = fmaf(w0, nv[i0*3+2], fmaf(w1, nv[i1*3+2], fmaf(w2, nv[i2*3+2], dz)));
    }
  }

  // reduce over 4 sub-slices within the wave (lanes pt, pt+16, pt+32, pt+48)
  sW += __shfl_xor(sW, 16, 64); dx += __shfl_xor(dx, 16, 64);
  dy += __shfl_xor(dy, 16, 64); dz += __shfl_xor(dz, 16, 64);
  sW += __shfl_xor(sW, 32, 64); dx += __shfl_xor(dx, 32, 64);
  dy += __shfl_xor(dy, 32, 64); dz += __shfl_xor(dz, 32, 64);

  if (sub == 0) {
    red[w][0][pt] = sW; red[w][1][pt] = dx;
    red[w][2][pt] = dy; red[w][3][pt] = dz;
  }
  __syncthreads();

  if (w == 0 && sub == 0) {
    float S = red[0][0][pt] + red[1][0][pt] + red[2][0][pt] + red[3][0][pt];
    float X = red[0][1][pt] + red[1][1][pt] + red[2][1][pt] + red[3][1][pt];
    float Y = red[0][2][pt] + red[1][2][pt] + red[2][2][pt] + red[3][2][pt];
    float Z = red[0][3][pt] + red[1][3][pt] + red[2][3][pt] + red[3][3][pt];
    S = (fabsf(S) > EPSF) ? S : EPSF;
    float inv = 1.0f / S;
    outDef[((size_t)b*6144 + p)*3 + 0] = X * inv;
    outDef[((size_t)b*6144 + p)*3 + 1] = Y * inv;
    outDef[((size_t)b*6144 + p)*3 + 2] = Z * inv;
  }
}

// ---------------------------------------------------------------------------
// Phase 3: chamfer mins, BOTH directions in one dispatch.
// Repartition: 16 col-chunks x 384 cols, grid = 2*4*6*16 = 768 = exactly
// 3 blocks/CU (was 1152 = 4.5/CU with a tail). Tile pre-scaled to
// (-2c, |c|^2): per pair = 3 chained fma + 1 fmin.
// ---------------------------------------------------------------------------
__global__ __launch_bounds__(256) void k_chamfer(
    const float* __restrict__ def,     // (B,6144,3)
    const float* __restrict__ ins,     // (B,6144,3)
    float*       __restrict__ outIns,  // (B,6144,3) copy of insModel
    unsigned*    __restrict__ mins)    // 2*B*6144 float-as-uint, pre-init +inf
{
  const int bx  = blockIdx.x;
  const int dir = (bx >= 384) ? 1 : 0;
  const int r   = bx - dir*384;
  const int b   = r / 96;
  const int rt  = (r % 96) / 16;
  const int cc  = r % 16;
  const int tid = threadIdx.x;

  const float* R = (dir ? ins : def) + (size_t)b * 6144 * 3;
  const float* C = (dir ? def : ins) + (size_t)b * 6144 * 3;

  const int r0 = rt*1024 + tid;
  const int r1 = r0 + 256, r2 = r0 + 512, r3 = r0 + 768;
  const float r0x = R[r0*3+0], r0y = R[r0*3+1], r0z = R[r0*3+2];
  const float r1x = R[r1*3+0], r1y = R[r1*3+1], r1z = R[r1*3+2];
  const float r2x = R[r2*3+0], r2y = R[r2*3+1], r2z = R[r2*3+2];
  const float r3x = R[r3*3+0], r3y = R[r3*3+1], r3z = R[r3*3+2];

  if (dir == 1 && cc == 0) {   // passthrough copy (output 1)
    outIns[(size_t)(b*6144 + r0)*3+0] = r0x; outIns[(size_t)(b*6144 + r0)*3+1] = r0y; outIns[(size_t)(b*6144 + r0)*3+2] = r0z;
    outIns[(size_t)(b*6144 + r1)*3+0] = r1x; outIns[(size_t)(b*6144 + r1)*3+1] = r1y; outIns[(size_t)(b*6144 + r1)*3+2] = r1z;
    outIns[(size_t)(b*6144 + r2)*3+0] = r2x; outIns[(size_t)(b*6144 + r2)*3+1] = r2y; outIns[(size_t)(b*6144 + r2)*3+2] = r2z;
    outIns[(size_t)(b*6144 + r3)*3+0] = r3x; outIns[(size_t)(b*6144 + r3)*3+1] = r3y; outIns[(size_t)(b*6144 + r3)*3+2] = r3z;
  }

  __shared__ float4 tile[384];
  #pragma unroll
  for (int c = tid; c < 384; c += 256) {
    int cg = cc*384 + c;
    float cx = C[cg*3+0], cy = C[cg*3+1], cz = C[cg*3+2];
    tile[c] = make_float4(-2.0f*cx, -2.0f*cy, -2.0f*cz, cx*cx + cy*cy + cz*cz);
  }
  __syncthreads();

  float m0 = 1e30f, m1 = 1e30f, m2 = 1e30f, m3 = 1e30f;
  #pragma unroll 8
  for (int j = 0; j < 384; ++j) {
    float4 q = tile[j];
    m0 = fminf(m0, fmaf(q.x, r0x, fmaf(q.y, r0y, fmaf(q.z, r0z, q.w))));
    m1 = fminf(m1, fmaf(q.x, r1x, fmaf(q.y, r1y, fmaf(q.z, r1z, q.w))));
    m2 = fminf(m2, fmaf(q.x, r2x, fmaf(q.y, r2y, fmaf(q.z, r2z, q.w))));
    m3 = fminf(m3, fmaf(q.x, r3x, fmaf(q.y, r3y, fmaf(q.z, r3z, q.w))));
  }

  unsigned* mo = mins + dir*24576 + b*6144;
  atomicMin(&mo[r0], __float_as_uint(m0 + (r0x*r0x + r0y*r0y + r0z*r0z)));
  atomicMin(&mo[r1], __float_as_uint(m1 + (r1x*r1x + r1y*r1y + r1z*r1z)));
  atomicMin(&mo[r2], __float_as_uint(m2 + (r2x*r2x + r2y*r2y + r2z*r2z)));
  atomicMin(&mo[r3], __float_as_uint(m3 + (r3x*r3x + r3y*r3y + r3z*r3z)));
}

// ---------------------------------------------------------------------------
// Phase 4: parallel loss reduction. 96 blocks x 512 elems; pre-scaled
// atomicAdd partials into loss (zeroed by k_init).
// ---------------------------------------------------------------------------
__global__ __launch_bounds__(256) void k_loss(
    const unsigned* __restrict__ mins,  // 2*24576 entries
    float* __restrict__ loss)
{
  const int base = blockIdx.x * 512 + threadIdx.x * 2;
  float s = __uint_as_float(mins[base]) + __uint_as_float(mins[base + 1]);
  #pragma unroll
  for (int off = 32; off; off >>= 1) s += __shfl_xor(s, off, 64);
  __shared__ float red[4];
  if ((threadIdx.x & 63) == 0) red[threadIdx.x >> 6] = s;
  __syncthreads();
  if (threadIdx.x == 0)
    atomicAdd(loss, (red[0] + red[1] + red[2] + red[3]) * (1.0f / 24576.0f));
}

// ---------------------------------------------------------------------------
extern "C" void kernel_launch(void* const* d_in, const int* in_sizes, int n_in,
                              void* d_out, int out_size, void* d_ws, size_t ws_size,
                              hipStream_t stream) {
  const float* catModel = (const float*)d_in[0];  // (4,6144,3)
  const float* catKeys  = (const float*)d_in[1];  // (4,8,3)
  const float* catInflu = (const float*)d_in[2];  // (4,8,42)
  const float* insKeys  = (const float*)d_in[3];  // (4,8,3)
  const float* insModel = (const float*)d_in[4];  // (4,6144,3)
  const float* tv       = (const float*)d_in[5];  // (1,3,42)
  // d_in[6] = template_faces, baked in as FI[][]

  float* out = (float*)d_out;       // [catModel | insModel | deformed | loss]
  float* ws  = (float*)d_ws;
  float*    cage  = ws;                       // 504 floats (pad to 512)
  float*    ncage = ws + 512;                 // 504 floats
  unsigned* mins  = (unsigned*)(ws + 1024);   // 49152 uints

  k_init<<<192, 256, 0, stream>>>(mins, 49152, out + 221184);
  k_cage<<<168, 512, 0, stream>>>(catModel, tv, catKeys, insKeys, catInflu, cage, ncage);
  k_mvc <<<1536, 256, 0, stream>>>(catModel, cage, ncage, out, out + 147456);
  k_chamfer<<<768, 256, 0, stream>>>(out + 147456, insModel, out + 73728, mins);
  k_loss<<<96, 256, 0, stream>>>(mins, out + 221184);
}